// Round 8
// baseline (435.209 us; speedup 1.0000x reference)
//
#include <hip/hip_runtime.h>
#include <hip/hip_cooperative_groups.h>
#include <stdint.h>

namespace cg = cooperative_groups;

#define COLUMNS   1024
#define CELLS     16
#define NUM_CELLS (COLUMNS * CELLS)   // 16384
#define SEGS      32
#define SYNS      128
#define ACT_THR   10

// cooperative geometry: 1024 blocks x 256 thr = 4 blocks/CU (launch_bounds 4 waves/EU)
#define NBLK      1024
#define TPB       256
#define NWAVE     (NBLK * (TPB / 64))                 // 4096 waves
#define MAXC      ((NUM_CELLS + NWAVE - 1) / NWAVE)   // 4 cells/wave max

// fallback (round-5 proven pipeline) geometry
#define FNB       2048
#define FWPB      4

// ws layout
#define WS_PREDW   0          // 64 KiB: per-cell pred words (cooperative path)
#define WS_FB      65536      // fallback small fields
#define WS_PACKED  131072     // 128 MiB u16 sideband (both paths)

typedef int            i32x4 __attribute__((ext_vector_type(4)));
typedef float          f32x4 __attribute__((ext_vector_type(4)));
typedef unsigned short u16x4 __attribute__((ext_vector_type(4)));

template<typename T>
__device__ __forceinline__ T ntload(const T* p) { return __builtin_nontemporal_load(p); }

// ===========================================================================
// Cooperative fused kernel
// ===========================================================================
template<bool PACK>
__global__ __launch_bounds__(TPB, 4) void fused_kernel(
    const void* __restrict__ prev, const int* __restrict__ x,
    const float* __restrict__ mod, const int* __restrict__ conn,
    const float* __restrict__ vol, const float* __restrict__ cons,
    unsigned short* __restrict__ packed, unsigned int* __restrict__ predw,
    float* __restrict__ out)
{
    __shared__ uint32_t sprev[NUM_CELLS / 32];
    __shared__ uint32_t snew[NUM_CELLS / 32];
    __shared__ unsigned short sacols[COLUMNS];
    __shared__ unsigned short s_na[COLUMNS];
    __shared__ unsigned char s_act[COLUMNS];
    __shared__ unsigned char s_hp[COLUMNS];
    __shared__ int s_isu8, s_any, s_gcnt[16], s_goff[16], s_acount, s_nact, s_npred;

    const int t  = threadIdx.x;
    const int wv = t >> 6;
    const int ln = t & 63;

    if (t == 0) { s_isu8 = 0; s_any = 0; s_nact = 0; s_npred = 0; }
    __syncthreads();

    // ---- prev dtype detect (int32-bool words are all 0/1; uint8-bool not) ----
    {
        const int* pi = (const int*)prev;
        int bad = 0;
        for (int k = t; k < NUM_CELLS / 4; k += TPB)
            bad |= ((unsigned)pi[k] > 1u) ? 1 : 0;
        unsigned long long bb = __ballot(bad != 0);
        if (ln == 0 && bb) atomicOr(&s_isu8, 1);
    }
    __syncthreads();
    // ---- pack prev bits into LDS ----
    {
        const int isu8 = s_isu8;
        const int* pi = (const int*)prev;
        int any = 0;
        for (int w = t; w < NUM_CELLS / 32; w += TPB) {
            uint32_t m = 0;
            if (isu8) {
                const unsigned char* p = (const unsigned char*)prev + (size_t)w * 32;
                #pragma unroll
                for (int j = 0; j < 32; ++j) m |= (p[j] ? 1u : 0u) << j;
            } else {
                const int* p = pi + (size_t)w * 32;
                #pragma unroll
                for (int j = 0; j < 32; ++j) m |= (p[j] ? 1u : 0u) << j;
            }
            sprev[w] = m;
            any |= (m != 0) ? 1 : 0;
        }
        unsigned long long ba = __ballot(any != 0);
        if (ln == 0 && ba) atomicOr(&s_any, 1);
    }
    // ---- ordered active-column compaction (column order preserved) ----
    int ca_[4];
    #pragma unroll
    for (int c2 = 0; c2 < 4; ++c2) {
        const int col = c2 * TPB + t;
        ca_[c2] = (x[col] != 0) ? 1 : 0;
        s_act[col] = (unsigned char)ca_[c2];
        unsigned long long b = __ballot(ca_[c2] != 0);
        if (ln == 0) s_gcnt[c2 * 4 + wv] = __popcll(b);
    }
    __syncthreads();
    if (t == 0) {
        int s = 0;
        #pragma unroll
        for (int g = 0; g < 16; ++g) { s_goff[g] = s; s += s_gcnt[g]; }
        s_acount = s;
    }
    __syncthreads();
    #pragma unroll
    for (int c2 = 0; c2 < 4; ++c2) {
        const int col = c2 * TPB + t;
        unsigned long long b = __ballot(ca_[c2] != 0);
        if (ca_[c2])
            sacols[s_goff[c2 * 4 + wv] + __popcll(b & ((1ULL << ln) - 1ULL))] =
                (unsigned short)col;
    }
    __syncthreads();

    const int nc   = s_acount * CELLS;
    const int lf   = ((mod[0] != 0.0f) && s_any) ? 1 : 0;
    const float d  = mod[0] * 0.1f;
    const int half = ln >> 5;
    const int l32  = ln & 31;
    const int gw   = blockIdx.x * (TPB / 64) + wv;

    // ---- Phase B: phases 1+2 over this wave's cells ----
    int my_cell[MAXC], my_bseg[MAXC];
    #pragma unroll
    for (int s = 0; s < MAXC; ++s) {
        my_cell[s] = -1; my_bseg[s] = 0;
        const int idx = gw + s * NWAVE;
        if (idx >= nc) continue;
        const int cell = (int)sacols[idx >> 4] * CELLS + (idx & 15);
        const size_t base = (size_t)cell * (SEGS * SYNS);
        int fire = 0, bestkey = 0;
        #pragma unroll 4
        for (int k = 0; k < 16; ++k) {
            const int segA = k * 2;               // lanes 0-31: segA, 32-63: segA+1
            const size_t off = base + (size_t)(segA + half) * SYNS + l32 * 4;
            i32x4 c = ntload((const i32x4*)(conn + off));
            f32x4 v = ntload((const f32x4*)(vol + off));
            f32x4 q = ntload((const f32x4*)(cons + off));
            int i0 = min(max(c.x, 0), NUM_CELLS - 1);
            int i1 = min(max(c.y, 0), NUM_CELLS - 1);
            int i2 = min(max(c.z, 0), NUM_CELLS - 1);
            int i3 = min(max(c.w, 0), NUM_CELLS - 1);
            int p0 = (sprev[i0 >> 5] >> (i0 & 31)) & 1;
            int p1 = (sprev[i1 >> 5] >> (i1 & 31)) & 1;
            int p2 = (sprev[i2 >> 5] >> (i2 & 31)) & 1;
            int p3 = (sprev[i3 >> 5] >> (i3 & 31)) & 1;
            int cn0 = ((v.x > 0.5f) || (q.x > 0.5f)) ? 1 : 0;
            int cn1 = ((v.y > 0.5f) || (q.y > 0.5f)) ? 1 : 0;
            int cn2 = ((v.z > 0.5f) || (q.z > 0.5f)) ? 1 : 0;
            int cn3 = ((v.w > 0.5f) || (q.w > 0.5f)) ? 1 : 0;
            if (PACK) {
                u16x4 pk;
                pk.x = (unsigned short)(i0 | (cn0 << 14));
                pk.y = (unsigned short)(i1 | (cn1 << 14));
                pk.z = (unsigned short)(i2 | (cn2 << 14));
                pk.w = (unsigned short)(i3 | (cn3 << 14));
                *(u16x4*)(packed + off) = pk;
            }
            unsigned long long bc0 = __ballot(cn0 && p0);
            unsigned long long bc1 = __ballot(cn1 && p1);
            unsigned long long bc2 = __ballot(cn2 && p2);
            unsigned long long bc3 = __ballot(cn3 && p3);
            unsigned long long bp0 = __ballot(p0 != 0);
            unsigned long long bp1 = __ballot(p1 != 0);
            unsigned long long bp2 = __ballot(p2 != 0);
            unsigned long long bp3 = __ballot(p3 != 0);
            int cA = __popcll(bc0 & 0xFFFFFFFFull) + __popcll(bc1 & 0xFFFFFFFFull)
                   + __popcll(bc2 & 0xFFFFFFFFull) + __popcll(bc3 & 0xFFFFFFFFull);
            int cB = __popcll(bc0 >> 32) + __popcll(bc1 >> 32)
                   + __popcll(bc2 >> 32) + __popcll(bc3 >> 32);
            int oA = __popcll(bp0 & 0xFFFFFFFFull) + __popcll(bp1 & 0xFFFFFFFFull)
                   + __popcll(bp2 & 0xFFFFFFFFull) + __popcll(bp3 & 0xFFFFFFFFull);
            int oB = __popcll(bp0 >> 32) + __popcll(bp1 >> 32)
                   + __popcll(bp2 >> 32) + __popcll(bp3 >> 32);
            fire |= (cA >= ACT_THR) | (cB >= ACT_THR);
            bestkey = max(bestkey, (oA << 8) | (255 - segA));   // first-max tiebreak
            bestkey = max(bestkey, (oB << 8) | (254 - segA));
        }
        my_cell[s] = cell;
        my_bseg[s] = 255 - (bestkey & 0xFF);
        if (ln == 0)   // device-scope: per-XCD L2s are not coherent (G16)
            __hip_atomic_store(&predw[cell], (unsigned)(fire ? 1 : 0),
                               __ATOMIC_RELAXED, __HIP_MEMORY_SCOPE_AGENT);
    }

    __threadfence();
    cg::this_grid().sync();

    // ---- Phase C prologue: rebuild newbits from predw (agent-scope loads) ----
    #pragma unroll
    for (int c2 = 0; c2 < 4; ++c2) {
        const int col = c2 * TPB + t;
        unsigned int bits = 0, hp = 0;
        if (s_act[col]) {
            unsigned int pb = 0;
            const unsigned int* pw = predw + (size_t)col * CELLS;
            #pragma unroll
            for (int c = 0; c < CELLS; ++c)
                pb |= (__hip_atomic_load(&pw[c], __ATOMIC_RELAXED,
                                         __HIP_MEMORY_SCOPE_AGENT) ? 1u : 0u) << c;
            hp = (pb != 0) ? 1u : 0u;
            bits = hp ? pb : 0xFFFFu;     // burst if no prediction
        }
        s_na[col] = (unsigned short)bits;
        s_hp[col] = (unsigned char)hp;
    }
    __syncthreads();
    for (int w = t; w < NUM_CELLS / 32; w += TPB)
        snew[w] = (uint32_t)s_na[2 * w] | ((uint32_t)s_na[2 * w + 1] << 16);
    __syncthreads();

    float* outpred = out + NUM_CELLS;
    // inactive-column zeros: block b owns column b (NBLK == COLUMNS)
    if (!s_act[blockIdx.x] && t < CELLS)
        outpred[blockIdx.x * CELLS + t] = 0.0f;

    if (blockIdx.x == 0) {
        int c1 = 0, cp = 0;
        #pragma unroll
        for (int c2 = 0; c2 < 4; ++c2) {
            const int col = c2 * TPB + t;
            c1 += s_act[col];
            cp += s_act[col] & s_hp[col];
        }
        atomicAdd(&s_nact, c1);
        atomicAdd(&s_npred, cp);
        for (int g = t; g < NUM_CELLS / 4; g += TPB) {
            const uint32_t w = snew[g >> 3];
            const int sh = (g & 7) * 4;
            f32x4 o;
            o.x = (w >> (sh + 0)) & 1 ? 1.0f : 0.0f;
            o.y = (w >> (sh + 1)) & 1 ? 1.0f : 0.0f;
            o.z = (w >> (sh + 2)) & 1 ? 1.0f : 0.0f;
            o.w = (w >> (sh + 3)) & 1 ? 1.0f : 0.0f;
            *(f32x4*)(out + (size_t)g * 4) = o;
        }
        __syncthreads();
        if (t == 0)
            out[2 * NUM_CELLS] = (s_nact > 0)
                ? (float)s_npred / (float)max(s_nact, 1) : 1.0f;
    }

    // ---- Phase C main: phase 3 over the SAME cells (bestseg in registers) ----
    #pragma unroll
    for (int s = 0; s < MAXC; ++s) {
        if (my_cell[s] < 0) continue;
        const int cell = my_cell[s];
        const size_t base = (size_t)cell * (SEGS * SYNS);
        const int na  = (snew[cell >> 5] >> (cell & 31)) & 1;
        const int upd = (lf && na) ? my_bseg[s] : -1;
        int fire = 0;
        #pragma unroll 4
        for (int k = 0; k < 16; ++k) {
            const int segA = k * 2;
            const int seg  = segA + half;
            const size_t off = base + (size_t)seg * SYNS + l32 * 4;
            int i0, i1, i2, i3, cn0, cn1, cn2, cn3;
            if (PACK) {
                u16x4 pk = *(const u16x4*)(packed + off);
                i0 = pk.x & 0x3FFF; cn0 = (pk.x >> 14) & 1;
                i1 = pk.y & 0x3FFF; cn1 = (pk.y >> 14) & 1;
                i2 = pk.z & 0x3FFF; cn2 = (pk.z >> 14) & 1;
                i3 = pk.w & 0x3FFF; cn3 = (pk.w >> 14) & 1;
                if (seg == upd) {
                    f32x4 v = *(const f32x4*)(vol + off);
                    f32x4 q = *(const f32x4*)(cons + off);
                    int pp0 = (sprev[i0 >> 5] >> (i0 & 31)) & 1;
                    int pp1 = (sprev[i1 >> 5] >> (i1 & 31)) & 1;
                    int pp2 = (sprev[i2 >> 5] >> (i2 & 31)) & 1;
                    int pp3 = (sprev[i3 >> 5] >> (i3 & 31)) & 1;
                    cn0 = ((v.x + (pp0 ? d : -d)) > 0.5f) || (q.x > 0.5f);
                    cn1 = ((v.y + (pp1 ? d : -d)) > 0.5f) || (q.y > 0.5f);
                    cn2 = ((v.z + (pp2 ? d : -d)) > 0.5f) || (q.z > 0.5f);
                    cn3 = ((v.w + (pp3 ? d : -d)) > 0.5f) || (q.w > 0.5f);
                }
            } else {
                i32x4 c = ntload((const i32x4*)(conn + off));
                f32x4 v = ntload((const f32x4*)(vol + off));
                f32x4 q = ntload((const f32x4*)(cons + off));
                i0 = min(max(c.x, 0), NUM_CELLS - 1);
                i1 = min(max(c.y, 0), NUM_CELLS - 1);
                i2 = min(max(c.z, 0), NUM_CELLS - 1);
                i3 = min(max(c.w, 0), NUM_CELLS - 1);
                float vx = v.x, vy = v.y, vz = v.z, vw = v.w;
                if (seg == upd) {
                    int pp0 = (sprev[i0 >> 5] >> (i0 & 31)) & 1;
                    int pp1 = (sprev[i1 >> 5] >> (i1 & 31)) & 1;
                    int pp2 = (sprev[i2 >> 5] >> (i2 & 31)) & 1;
                    int pp3 = (sprev[i3 >> 5] >> (i3 & 31)) & 1;
                    vx += pp0 ? d : -d; vy += pp1 ? d : -d;
                    vz += pp2 ? d : -d; vw += pp3 ? d : -d;
                }
                cn0 = (vx > 0.5f) || (q.x > 0.5f);
                cn1 = (vy > 0.5f) || (q.y > 0.5f);
                cn2 = (vz > 0.5f) || (q.z > 0.5f);
                cn3 = (vw > 0.5f) || (q.w > 0.5f);
            }
            int pn0 = (snew[i0 >> 5] >> (i0 & 31)) & 1;
            int pn1 = (snew[i1 >> 5] >> (i1 & 31)) & 1;
            int pn2 = (snew[i2 >> 5] >> (i2 & 31)) & 1;
            int pn3 = (snew[i3 >> 5] >> (i3 & 31)) & 1;
            unsigned long long b0 = __ballot(cn0 && pn0);
            unsigned long long b1 = __ballot(cn1 && pn1);
            unsigned long long b2 = __ballot(cn2 && pn2);
            unsigned long long b3 = __ballot(cn3 && pn3);
            int cA = __popcll(b0 & 0xFFFFFFFFull) + __popcll(b1 & 0xFFFFFFFFull)
                   + __popcll(b2 & 0xFFFFFFFFull) + __popcll(b3 & 0xFFFFFFFFull);
            int cB = __popcll(b0 >> 32) + __popcll(b1 >> 32)
                   + __popcll(b2 >> 32) + __popcll(b3 >> 32);
            fire |= (cA >= ACT_THR) | (cB >= ACT_THR);
        }
        if (ln == 0) outpred[cell] = fire ? 1.0f : 0.0f;
    }
}

// ===========================================================================
// Fallback: round-5 proven 4-kernel pipeline (137 us)
// ===========================================================================
__global__ __launch_bounds__(1024) void plan_kernel(
    const void* __restrict__ prev, const int* __restrict__ x,
    const float* __restrict__ mod, uint32_t* __restrict__ prevbits,
    int* __restrict__ acols, int* __restrict__ acount, int* __restrict__ learnflag)
{
    __shared__ int s_isu8, s_any;
    __shared__ int wcnt[16], woff[16];
    const int t = threadIdx.x;
    const int* pi = (const int*)prev;
    if (t == 0) { s_isu8 = 0; s_any = 0; }
    __syncthreads();
    int bad = 0;
    for (int k = t; k < NUM_CELLS / 4; k += 1024)
        if ((unsigned)pi[k] > 1u) bad = 1;
    if (bad) atomicOr(&s_isu8, 1);
    __syncthreads();
    if (t < 512) {
        uint32_t m = 0;
        if (s_isu8) {
            const unsigned char* p = (const unsigned char*)prev + (size_t)t * 32;
            #pragma unroll
            for (int j = 0; j < 32; ++j) m |= (p[j] ? 1u : 0u) << j;
        } else {
            const int* p = pi + (size_t)t * 32;
            #pragma unroll
            for (int j = 0; j < 32; ++j) m |= (p[j] ? 1u : 0u) << j;
        }
        prevbits[t] = m;
        if (m) atomicOr(&s_any, 1);
    }
    const int ca = (x[t] != 0) ? 1 : 0;
    unsigned long long b = __ballot(ca != 0);
    const int wid = t >> 6, ln = t & 63;
    if (ln == 0) wcnt[wid] = __popcll(b);
    __syncthreads();
    if (t == 0) {
        int s = 0;
        for (int i = 0; i < 16; ++i) { woff[i] = s; s += wcnt[i]; }
        *acount = s;
        *learnflag = ((mod[0] != 0.0f) && s_any) ? 1 : 0;
    }
    __syncthreads();
    if (ca) acols[woff[wid] + __popcll(b & ((1ULL << ln) - 1ULL))] = t;
}

template<bool PACK>
__global__ __launch_bounds__(256) void phase1_kernel(
    const uint32_t* __restrict__ prevbits, const int* __restrict__ acols,
    const int* __restrict__ acount,
    const int* __restrict__ conn, const float* __restrict__ vol,
    const float* __restrict__ cons, unsigned short* __restrict__ packed,
    unsigned char* __restrict__ pred1, unsigned char* __restrict__ bestseg)
{
    __shared__ uint32_t sbits[NUM_CELLS / 32];
    for (int i = threadIdx.x; i < NUM_CELLS / 32; i += 256) sbits[i] = prevbits[i];
    __syncthreads();
    const int nc   = *acount * CELLS;
    const int wv   = threadIdx.x >> 6;
    const int ln   = threadIdx.x & 63;
    const int half = ln >> 5;
    const int l32  = ln & 31;
    const int gw   = blockIdx.x * FWPB + wv;
    for (int idx = gw; idx < nc; idx += FNB * FWPB) {
        const int cell = acols[idx >> 4] * CELLS + (idx & 15);
        const size_t base = (size_t)cell * (SEGS * SYNS);
        int fire = 0, bestkey = 0;
        #pragma unroll 4
        for (int k = 0; k < 16; ++k) {
            const int segA = k * 2;
            const size_t off = base + (size_t)(segA + half) * SYNS + l32 * 4;
            i32x4 c = ntload((const i32x4*)(conn + off));
            f32x4 v = ntload((const f32x4*)(vol + off));
            f32x4 q = ntload((const f32x4*)(cons + off));
            int i0 = min(max(c.x, 0), NUM_CELLS - 1);
            int i1 = min(max(c.y, 0), NUM_CELLS - 1);
            int i2 = min(max(c.z, 0), NUM_CELLS - 1);
            int i3 = min(max(c.w, 0), NUM_CELLS - 1);
            int p0 = (sbits[i0 >> 5] >> (i0 & 31)) & 1;
            int p1 = (sbits[i1 >> 5] >> (i1 & 31)) & 1;
            int p2 = (sbits[i2 >> 5] >> (i2 & 31)) & 1;
            int p3 = (sbits[i3 >> 5] >> (i3 & 31)) & 1;
            int cn0 = ((v.x > 0.5f) || (q.x > 0.5f)) ? 1 : 0;
            int cn1 = ((v.y > 0.5f) || (q.y > 0.5f)) ? 1 : 0;
            int cn2 = ((v.z > 0.5f) || (q.z > 0.5f)) ? 1 : 0;
            int cn3 = ((v.w > 0.5f) || (q.w > 0.5f)) ? 1 : 0;
            if (PACK) {
                u16x4 pk;
                pk.x = (unsigned short)(i0 | (cn0 << 14));
                pk.y = (unsigned short)(i1 | (cn1 << 14));
                pk.z = (unsigned short)(i2 | (cn2 << 14));
                pk.w = (unsigned short)(i3 | (cn3 << 14));
                *(u16x4*)(packed + off) = pk;
            }
            unsigned long long bc0 = __ballot(cn0 && p0);
            unsigned long long bc1 = __ballot(cn1 && p1);
            unsigned long long bc2 = __ballot(cn2 && p2);
            unsigned long long bc3 = __ballot(cn3 && p3);
            unsigned long long bp0 = __ballot(p0 != 0);
            unsigned long long bp1 = __ballot(p1 != 0);
            unsigned long long bp2 = __ballot(p2 != 0);
            unsigned long long bp3 = __ballot(p3 != 0);
            int cA = __popcll(bc0 & 0xFFFFFFFFull) + __popcll(bc1 & 0xFFFFFFFFull)
                   + __popcll(bc2 & 0xFFFFFFFFull) + __popcll(bc3 & 0xFFFFFFFFull);
            int cB = __popcll(bc0 >> 32) + __popcll(bc1 >> 32)
                   + __popcll(bc2 >> 32) + __popcll(bc3 >> 32);
            int oA = __popcll(bp0 & 0xFFFFFFFFull) + __popcll(bp1 & 0xFFFFFFFFull)
                   + __popcll(bp2 & 0xFFFFFFFFull) + __popcll(bp3 & 0xFFFFFFFFull);
            int oB = __popcll(bp0 >> 32) + __popcll(bp1 >> 32)
                   + __popcll(bp2 >> 32) + __popcll(bp3 >> 32);
            fire |= (cA >= ACT_THR) | (cB >= ACT_THR);
            bestkey = max(bestkey, (oA << 8) | (255 - segA));
            bestkey = max(bestkey, (oB << 8) | (254 - segA));
        }
        if (ln == 0) {
            pred1[cell]   = (unsigned char)(fire ? 1 : 0);
            bestseg[cell] = (unsigned char)(255 - (bestkey & 0xFF));
        }
    }
}

__global__ __launch_bounds__(1024) void mid_kernel(
    const int* __restrict__ x, const unsigned char* __restrict__ pred1,
    uint32_t* __restrict__ newbits, float* __restrict__ out)
{
    __shared__ unsigned char s_hp[COLUMNS];
    __shared__ unsigned char s_act[COLUMNS];
    __shared__ int s_nact, s_npred;
    const int t = threadIdx.x;
    if (t == 0) { s_nact = 0; s_npred = 0; }
    __syncthreads();
    {
        const int col = t;
        int ca = (x[col] != 0) ? 1 : 0;
        int hp = 0;
        if (ca) {
            #pragma unroll
            for (int k = 0; k < CELLS; ++k) hp |= pred1[col * CELLS + k];
            hp = hp ? 1 : 0;
        }
        s_act[col] = (unsigned char)ca;
        s_hp[col]  = (unsigned char)hp;
        unsigned long long ba = __ballot(ca != 0);
        unsigned long long bp = __ballot((ca && hp) != 0);
        if ((t & 63) == 0) {
            atomicAdd(&s_nact, __popcll(ba));
            atomicAdd(&s_npred, __popcll(bp));
        }
    }
    __syncthreads();
    if (t < NUM_CELLS / 32) {
        uint32_t m = 0;
        #pragma unroll
        for (int j = 0; j < 32; ++j) {
            const int cell = t * 32 + j;
            const int col  = cell >> 4;
            int na = s_act[col] && (s_hp[col] ? (pred1[cell] != 0) : 1);
            m |= (uint32_t)(na ? 1u : 0u) << j;
        }
        newbits[t] = m;
    }
    for (int i = t; i < NUM_CELLS; i += 1024) {
        const int col = i >> 4;
        int na = s_act[col] && (s_hp[col] ? (pred1[i] != 0) : 1);
        out[i] = na ? 1.0f : 0.0f;
        out[NUM_CELLS + i] = 0.0f;
    }
    __syncthreads();
    if (t == 0) {
        float acc = (s_nact > 0) ? (float)s_npred / (float)max(s_nact, 1) : 1.0f;
        out[2 * NUM_CELLS] = acc;
    }
}

template<bool PACKED>
__global__ __launch_bounds__(256) void phase3_kernel(
    const uint32_t* __restrict__ prevbits, const uint32_t* __restrict__ newbits,
    const int* __restrict__ acols, const int* __restrict__ acount,
    const int* __restrict__ learnflag, const float* __restrict__ mod,
    const unsigned short* __restrict__ packed, const int* __restrict__ conn,
    const float* __restrict__ vol, const float* __restrict__ cons,
    const unsigned char* __restrict__ bestseg, float* __restrict__ outpred)
{
    __shared__ uint32_t snew[NUM_CELLS / 32];
    __shared__ uint32_t sprev[NUM_CELLS / 32];
    for (int i = threadIdx.x; i < NUM_CELLS / 32; i += 256) {
        snew[i]  = newbits[i];
        sprev[i] = prevbits[i];
    }
    __syncthreads();
    const int nc   = *acount * CELLS;
    const int lf   = *learnflag;
    const float d  = mod[0] * 0.1f;
    const int wv   = threadIdx.x >> 6;
    const int ln   = threadIdx.x & 63;
    const int half = ln >> 5;
    const int l32  = ln & 31;
    const int gw   = blockIdx.x * FWPB + wv;
    for (int idx = gw; idx < nc; idx += FNB * FWPB) {
        const int cell = acols[idx >> 4] * CELLS + (idx & 15);
        const size_t base = (size_t)cell * (SEGS * SYNS);
        const int na  = (snew[cell >> 5] >> (cell & 31)) & 1;
        const int upd = (lf && na) ? (int)bestseg[cell] : -1;
        int fire = 0;
        #pragma unroll 4
        for (int k = 0; k < 16; ++k) {
            const int segA = k * 2;
            const int seg  = segA + half;
            const size_t off = base + (size_t)seg * SYNS + l32 * 4;
            int i0, i1, i2, i3, cn0, cn1, cn2, cn3;
            if (PACKED) {
                u16x4 pk = *(const u16x4*)(packed + off);
                i0 = pk.x & 0x3FFF; cn0 = (pk.x >> 14) & 1;
                i1 = pk.y & 0x3FFF; cn1 = (pk.y >> 14) & 1;
                i2 = pk.z & 0x3FFF; cn2 = (pk.z >> 14) & 1;
                i3 = pk.w & 0x3FFF; cn3 = (pk.w >> 14) & 1;
                if (seg == upd) {
                    f32x4 v = *(const f32x4*)(vol + off);
                    f32x4 q = *(const f32x4*)(cons + off);
                    int pp0 = (sprev[i0 >> 5] >> (i0 & 31)) & 1;
                    int pp1 = (sprev[i1 >> 5] >> (i1 & 31)) & 1;
                    int pp2 = (sprev[i2 >> 5] >> (i2 & 31)) & 1;
                    int pp3 = (sprev[i3 >> 5] >> (i3 & 31)) & 1;
                    cn0 = ((v.x + (pp0 ? d : -d)) > 0.5f) || (q.x > 0.5f);
                    cn1 = ((v.y + (pp1 ? d : -d)) > 0.5f) || (q.y > 0.5f);
                    cn2 = ((v.z + (pp2 ? d : -d)) > 0.5f) || (q.z > 0.5f);
                    cn3 = ((v.w + (pp3 ? d : -d)) > 0.5f) || (q.w > 0.5f);
                }
            } else {
                i32x4 c = ntload((const i32x4*)(conn + off));
                f32x4 v = ntload((const f32x4*)(vol + off));
                f32x4 q = ntload((const f32x4*)(cons + off));
                i0 = min(max(c.x, 0), NUM_CELLS - 1);
                i1 = min(max(c.y, 0), NUM_CELLS - 1);
                i2 = min(max(c.z, 0), NUM_CELLS - 1);
                i3 = min(max(c.w, 0), NUM_CELLS - 1);
                float vx = v.x, vy = v.y, vz = v.z, vw = v.w;
                if (seg == upd) {
                    int pp0 = (sprev[i0 >> 5] >> (i0 & 31)) & 1;
                    int pp1 = (sprev[i1 >> 5] >> (i1 & 31)) & 1;
                    int pp2 = (sprev[i2 >> 5] >> (i2 & 31)) & 1;
                    int pp3 = (sprev[i3 >> 5] >> (i3 & 31)) & 1;
                    vx += pp0 ? d : -d; vy += pp1 ? d : -d;
                    vz += pp2 ? d : -d; vw += pp3 ? d : -d;
                }
                cn0 = (vx > 0.5f) || (q.x > 0.5f);
                cn1 = (vy > 0.5f) || (q.y > 0.5f);
                cn2 = (vz > 0.5f) || (q.z > 0.5f);
                cn3 = (vw > 0.5f) || (q.w > 0.5f);
            }
            int pn0 = (snew[i0 >> 5] >> (i0 & 31)) & 1;
            int pn1 = (snew[i1 >> 5] >> (i1 & 31)) & 1;
            int pn2 = (snew[i2 >> 5] >> (i2 & 31)) & 1;
            int pn3 = (snew[i3 >> 5] >> (i3 & 31)) & 1;
            unsigned long long b0 = __ballot(cn0 && pn0);
            unsigned long long b1 = __ballot(cn1 && pn1);
            unsigned long long b2 = __ballot(cn2 && pn2);
            unsigned long long b3 = __ballot(cn3 && pn3);
            int cA = __popcll(b0 & 0xFFFFFFFFull) + __popcll(b1 & 0xFFFFFFFFull)
                   + __popcll(b2 & 0xFFFFFFFFull) + __popcll(b3 & 0xFFFFFFFFull);
            int cB = __popcll(b0 >> 32) + __popcll(b1 >> 32)
                   + __popcll(b2 >> 32) + __popcll(b3 >> 32);
            fire |= (cA >= ACT_THR) | (cB >= ACT_THR);
        }
        if (ln == 0) outpred[cell] = fire ? 1.0f : 0.0f;
    }
}

// ===========================================================================
extern "C" void kernel_launch(void* const* d_in, const int* in_sizes, int n_in,
                              void* d_out, int out_size, void* d_ws, size_t ws_size,
                              hipStream_t stream) {
    const void*  prev = d_in[2];
    const int*   x    = (const int*)d_in[0];
    const float* mod  = (const float*)d_in[1];
    const int*   conn = (const int*)d_in[3];
    const float* vol  = (const float*)d_in[4];
    const float* cons = (const float*)d_in[5];
    float* out = (float*)d_out;

    char* ws = (char*)d_ws;
    unsigned int*   predw  = (unsigned int*)(ws + WS_PREDW);
    unsigned short* packed = (unsigned short*)(ws + WS_PACKED);
    const size_t packed_bytes = (size_t)NUM_CELLS * SEGS * SYNS * 2;  // 128 MiB
    const bool use_packed = ws_size >= (size_t)WS_PACKED + packed_bytes;

    bool coop_ok = false;
    if (use_packed) {
        void* kprev = (void*)prev; void* kx = (void*)x; void* kmod = (void*)mod;
        void* kconn = (void*)conn; void* kvol = (void*)vol; void* kcons = (void*)cons;
        void* kpk = (void*)packed; void* kpw = (void*)predw; void* kout = (void*)out;
        void* args[] = {&kprev, &kx, &kmod, &kconn, &kvol, &kcons, &kpk, &kpw, &kout};
        hipError_t e = hipLaunchCooperativeKernel(
            reinterpret_cast<const void*>(&fused_kernel<true>),
            dim3(NBLK), dim3(TPB), args, 0, stream);
        coop_ok = (e == hipSuccess);
    }
    if (!coop_ok) {
        // proven round-5 pipeline
        uint32_t* prevbits  = (uint32_t*)(ws + WS_FB);
        uint32_t* newbits   = (uint32_t*)(ws + WS_FB + 2048);
        int*      learnflag = (int*)(ws + WS_FB + 4096);
        int*      acount    = (int*)(ws + WS_FB + 4160);
        int*      acols     = (int*)(ws + WS_FB + 4352);
        unsigned char* pred1   = (unsigned char*)(ws + WS_FB + 16384);
        unsigned char* bestseg = (unsigned char*)(ws + WS_FB + 32768);
        plan_kernel<<<1, 1024, 0, stream>>>(prev, x, mod, prevbits, acols, acount,
                                            learnflag);
        if (use_packed) {
            phase1_kernel<true><<<FNB, 256, 0, stream>>>(prevbits, acols, acount,
                conn, vol, cons, packed, pred1, bestseg);
            mid_kernel<<<1, 1024, 0, stream>>>(x, pred1, newbits, out);
            phase3_kernel<true><<<FNB, 256, 0, stream>>>(prevbits, newbits, acols,
                acount, learnflag, mod, packed, conn, vol, cons, bestseg,
                out + NUM_CELLS);
        } else {
            phase1_kernel<false><<<FNB, 256, 0, stream>>>(prevbits, acols, acount,
                conn, vol, cons, packed, pred1, bestseg);
            mid_kernel<<<1, 1024, 0, stream>>>(x, pred1, newbits, out);
            phase3_kernel<false><<<FNB, 256, 0, stream>>>(prevbits, newbits, acols,
                acount, learnflag, mod, packed, conn, vol, cons, bestseg,
                out + NUM_CELLS);
        }
    }
}

// Round 9
// 57.985 us; speedup vs baseline: 7.5056x; 7.5056x over previous
//
#include <hip/hip_runtime.h>
#include <stdint.h>

#define COLUMNS   1024
#define CELLS     16
#define NUM_CELLS (COLUMNS * CELLS)   // 16384
#define SEGS      32
#define SYNS      128
#define ACT_THR   10
#define NB        2048                // blocks for the big scans
#define WPB       4                   // waves per block (256 threads)

typedef int            i32x4 __attribute__((ext_vector_type(4)));
typedef float          f32x4 __attribute__((ext_vector_type(4)));

template<typename T>
__device__ __forceinline__ T ntload(const T* p) { return __builtin_nontemporal_load(p); }

// ---------------------------------------------------------------------------
// Plan kernel (1 block, 1024 thr): pack prev bits (dtype auto-detect),
// ordered compaction of active columns, learnflag.
// ---------------------------------------------------------------------------
__global__ __launch_bounds__(1024) void plan_kernel(
    const void* __restrict__ prev, const int* __restrict__ x,
    const float* __restrict__ mod, uint32_t* __restrict__ prevbits,
    int* __restrict__ acols, int* __restrict__ acount, int* __restrict__ learnflag)
{
    __shared__ int s_isu8, s_any;
    __shared__ int wcnt[16], woff[16];
    const int t = threadIdx.x;
    const int* pi = (const int*)prev;
    if (t == 0) { s_isu8 = 0; s_any = 0; }
    __syncthreads();
    // int32-bool: every word 0/1. uint8-bool (random 0/1 bytes): a word >1 whp.
    int bad = 0;
    for (int k = t; k < NUM_CELLS / 4; k += 1024)
        if ((unsigned)pi[k] > 1u) bad = 1;
    if (bad) atomicOr(&s_isu8, 1);
    __syncthreads();

    if (t < 512) {
        uint32_t m = 0;
        if (s_isu8) {
            const unsigned char* p = (const unsigned char*)prev + (size_t)t * 32;
            #pragma unroll
            for (int j = 0; j < 32; ++j) m |= (p[j] ? 1u : 0u) << j;
        } else {
            const int* p = pi + (size_t)t * 32;
            #pragma unroll
            for (int j = 0; j < 32; ++j) m |= (p[j] ? 1u : 0u) << j;
        }
        prevbits[t] = m;
        if (m) atomicOr(&s_any, 1);
    }

    // ordered active-column compaction (1024 threads = 16 waves)
    const int ca = (x[t] != 0) ? 1 : 0;
    unsigned long long b = __ballot(ca != 0);
    const int wid = t >> 6, ln = t & 63;
    if (ln == 0) wcnt[wid] = __popcll(b);
    __syncthreads();
    if (t == 0) {
        int s = 0;
        for (int i = 0; i < 16; ++i) { woff[i] = s; s += wcnt[i]; }
        *acount = s;
        *learnflag = ((mod[0] != 0.0f) && s_any) ? 1 : 0;
    }
    __syncthreads();
    if (ca) acols[woff[wid] + __popcll(b & ((1ULL << ln) - 1ULL))] = t;
}

// ---------------------------------------------------------------------------
// Phase 1+2 fused: persistent wave-per-cell over compacted active cells.
// conn+prev overlap is computed for ALL 32 segments (argmax needs it), but
// vol/cons are loaded ONLY while the fire bit is undecided (wave-uniform
// early exit) — with dense data that is one seg-pair instead of 16.
// ---------------------------------------------------------------------------
__global__ __launch_bounds__(256) void phase1_kernel(
    const uint32_t* __restrict__ prevbits, const int* __restrict__ acols,
    const int* __restrict__ acount,
    const int* __restrict__ conn, const float* __restrict__ vol,
    const float* __restrict__ cons,
    unsigned char* __restrict__ pred1, unsigned char* __restrict__ bestseg)
{
    __shared__ uint32_t sbits[NUM_CELLS / 32];
    for (int i = threadIdx.x; i < NUM_CELLS / 32; i += 256) sbits[i] = prevbits[i];
    __syncthreads();

    const int nc   = *acount * CELLS;
    const int wv   = threadIdx.x >> 6;
    const int ln   = threadIdx.x & 63;
    const int half = ln >> 5;
    const int l32  = ln & 31;
    const int gw   = blockIdx.x * WPB + wv;   // global wave id

    for (int idx = gw; idx < nc; idx += NB * WPB) {
        const int cell = acols[idx >> 4] * CELLS + (idx & 15);
        const size_t base = (size_t)cell * (SEGS * SYNS);
        int fire = 0, bestkey = 0;
        #pragma unroll 4
        for (int k = 0; k < 16; ++k) {
            const int segA = k * 2;               // lanes 0-31: segA, 32-63: segA+1
            const size_t off = base + (size_t)(segA + half) * SYNS + l32 * 4;
            i32x4 c = ntload((const i32x4*)(conn + off));
            int i0 = min(max(c.x, 0), NUM_CELLS - 1);
            int i1 = min(max(c.y, 0), NUM_CELLS - 1);
            int i2 = min(max(c.z, 0), NUM_CELLS - 1);
            int i3 = min(max(c.w, 0), NUM_CELLS - 1);
            int p0 = (sbits[i0 >> 5] >> (i0 & 31)) & 1;
            int p1 = (sbits[i1 >> 5] >> (i1 & 31)) & 1;
            int p2 = (sbits[i2 >> 5] >> (i2 & 31)) & 1;
            int p3 = (sbits[i3 >> 5] >> (i3 & 31)) & 1;
            unsigned long long bp0 = __ballot(p0 != 0);
            unsigned long long bp1 = __ballot(p1 != 0);
            unsigned long long bp2 = __ballot(p2 != 0);
            unsigned long long bp3 = __ballot(p3 != 0);
            int oA = __popcll(bp0 & 0xFFFFFFFFull) + __popcll(bp1 & 0xFFFFFFFFull)
                   + __popcll(bp2 & 0xFFFFFFFFull) + __popcll(bp3 & 0xFFFFFFFFull);
            int oB = __popcll(bp0 >> 32) + __popcll(bp1 >> 32)
                   + __popcll(bp2 >> 32) + __popcll(bp3 >> 32);
            bestkey = max(bestkey, (oA << 8) | (255 - segA));   // first-max tiebreak
            bestkey = max(bestkey, (oB << 8) | (254 - segA));
            if (!fire) {   // wave-uniform: skip vol/cons once decided
                f32x4 v = ntload((const f32x4*)(vol + off));
                f32x4 q = ntload((const f32x4*)(cons + off));
                int cn0 = ((v.x > 0.5f) || (q.x > 0.5f)) ? 1 : 0;
                int cn1 = ((v.y > 0.5f) || (q.y > 0.5f)) ? 1 : 0;
                int cn2 = ((v.z > 0.5f) || (q.z > 0.5f)) ? 1 : 0;
                int cn3 = ((v.w > 0.5f) || (q.w > 0.5f)) ? 1 : 0;
                unsigned long long bc0 = __ballot(cn0 && p0);
                unsigned long long bc1 = __ballot(cn1 && p1);
                unsigned long long bc2 = __ballot(cn2 && p2);
                unsigned long long bc3 = __ballot(cn3 && p3);
                int cA = __popcll(bc0 & 0xFFFFFFFFull) + __popcll(bc1 & 0xFFFFFFFFull)
                       + __popcll(bc2 & 0xFFFFFFFFull) + __popcll(bc3 & 0xFFFFFFFFull);
                int cB = __popcll(bc0 >> 32) + __popcll(bc1 >> 32)
                       + __popcll(bc2 >> 32) + __popcll(bc3 >> 32);
                fire |= (cA >= ACT_THR) | (cB >= ACT_THR);
            }
        }
        if (ln == 0) {
            pred1[cell]   = (unsigned char)(fire ? 1 : 0);
            bestseg[cell] = (unsigned char)(255 - (bestkey & 0xFF));
        }
    }
}

// ---------------------------------------------------------------------------
// Mid (1 block, 1024 thr = 1 col/thread): col_has_pred, new_active floats +
// packed bits, acc; zero-fills new_predictive (phase3 overwrites active cells).
// ---------------------------------------------------------------------------
__global__ __launch_bounds__(1024) void mid_kernel(
    const int* __restrict__ x, const unsigned char* __restrict__ pred1,
    uint32_t* __restrict__ newbits, float* __restrict__ out)
{
    __shared__ unsigned char s_hp[COLUMNS];
    __shared__ unsigned char s_act[COLUMNS];
    __shared__ int s_nact, s_npred;
    const int t = threadIdx.x;
    if (t == 0) { s_nact = 0; s_npred = 0; }
    __syncthreads();

    {
        const int col = t;
        int ca = (x[col] != 0) ? 1 : 0;
        int hp = 0;
        if (ca) {
            #pragma unroll
            for (int k = 0; k < CELLS; ++k) hp |= pred1[col * CELLS + k];
            hp = hp ? 1 : 0;
        }
        s_act[col] = (unsigned char)ca;
        s_hp[col]  = (unsigned char)hp;
        unsigned long long ba = __ballot(ca != 0);
        unsigned long long bp = __ballot((ca && hp) != 0);
        if ((t & 63) == 0) {
            atomicAdd(&s_nact, __popcll(ba));
            atomicAdd(&s_npred, __popcll(bp));
        }
    }
    __syncthreads();

    if (t < NUM_CELLS / 32) {
        uint32_t m = 0;
        #pragma unroll
        for (int j = 0; j < 32; ++j) {
            const int cell = t * 32 + j;
            const int col  = cell >> 4;
            int na = s_act[col] && (s_hp[col] ? (pred1[cell] != 0) : 1);
            m |= (uint32_t)(na ? 1u : 0u) << j;
        }
        newbits[t] = m;
    }
    for (int i = t; i < NUM_CELLS; i += 1024) {
        const int col = i >> 4;
        int na = s_act[col] && (s_hp[col] ? (pred1[i] != 0) : 1);
        out[i] = na ? 1.0f : 0.0f;
        out[NUM_CELLS + i] = 0.0f;   // default new_predictive (inactive cols)
    }
    __syncthreads();

    if (t == 0) {
        float acc = (s_nact > 0) ? (float)s_npred / (float)max(s_nact, 1) : 1.0f;
        out[2 * NUM_CELLS] = acc;
    }
}

// ---------------------------------------------------------------------------
// Phase 3: persistent wave-per-cell over compacted active cells, with
// EARLY EXIT: pred is any-over-segments, so stop at the first firing
// segment-pair (exact). The single updated segment of a winner cell applies
// the learning delta inline when reached (clip(x,0,1)>0.5 == x>0.5, exact).
// Typical cost: 1 seg-pair of conn/vol/cons per cell instead of 16.
// ---------------------------------------------------------------------------
__global__ __launch_bounds__(256) void phase3_kernel(
    const uint32_t* __restrict__ prevbits, const uint32_t* __restrict__ newbits,
    const int* __restrict__ acols, const int* __restrict__ acount,
    const int* __restrict__ learnflag, const float* __restrict__ mod,
    const int* __restrict__ conn, const float* __restrict__ vol,
    const float* __restrict__ cons, const unsigned char* __restrict__ bestseg,
    float* __restrict__ outpred)
{
    __shared__ uint32_t snew[NUM_CELLS / 32];
    __shared__ uint32_t sprev[NUM_CELLS / 32];
    for (int i = threadIdx.x; i < NUM_CELLS / 32; i += 256) {
        snew[i]  = newbits[i];
        sprev[i] = prevbits[i];
    }
    __syncthreads();

    const int nc   = *acount * CELLS;
    const int lf   = *learnflag;
    const float d  = mod[0] * 0.1f;
    const int wv   = threadIdx.x >> 6;
    const int ln   = threadIdx.x & 63;
    const int half = ln >> 5;
    const int l32  = ln & 31;
    const int gw   = blockIdx.x * WPB + wv;

    for (int idx = gw; idx < nc; idx += NB * WPB) {
        const int cell = acols[idx >> 4] * CELLS + (idx & 15);
        const size_t base = (size_t)cell * (SEGS * SYNS);
        const int na  = (snew[cell >> 5] >> (cell & 31)) & 1;
        const int upd = (lf && na) ? (int)bestseg[cell] : -1;
        int fire = 0;
        for (int k = 0; k < 16; ++k) {          // no unroll: early exit
            const int seg = k * 2 + half;
            const size_t off = base + (size_t)seg * SYNS + l32 * 4;
            i32x4 c = ntload((const i32x4*)(conn + off));
            f32x4 v = ntload((const f32x4*)(vol + off));
            f32x4 q = ntload((const f32x4*)(cons + off));
            int i0 = min(max(c.x, 0), NUM_CELLS - 1);
            int i1 = min(max(c.y, 0), NUM_CELLS - 1);
            int i2 = min(max(c.z, 0), NUM_CELLS - 1);
            int i3 = min(max(c.w, 0), NUM_CELLS - 1);
            float vx = v.x, vy = v.y, vz = v.z, vw = v.w;
            if (seg == upd) {
                int pp0 = (sprev[i0 >> 5] >> (i0 & 31)) & 1;
                int pp1 = (sprev[i1 >> 5] >> (i1 & 31)) & 1;
                int pp2 = (sprev[i2 >> 5] >> (i2 & 31)) & 1;
                int pp3 = (sprev[i3 >> 5] >> (i3 & 31)) & 1;
                vx += pp0 ? d : -d; vy += pp1 ? d : -d;
                vz += pp2 ? d : -d; vw += pp3 ? d : -d;
            }
            int cn0 = (vx > 0.5f) || (q.x > 0.5f);
            int cn1 = (vy > 0.5f) || (q.y > 0.5f);
            int cn2 = (vz > 0.5f) || (q.z > 0.5f);
            int cn3 = (vw > 0.5f) || (q.w > 0.5f);
            int pn0 = (snew[i0 >> 5] >> (i0 & 31)) & 1;
            int pn1 = (snew[i1 >> 5] >> (i1 & 31)) & 1;
            int pn2 = (snew[i2 >> 5] >> (i2 & 31)) & 1;
            int pn3 = (snew[i3 >> 5] >> (i3 & 31)) & 1;
            unsigned long long b0 = __ballot(cn0 && pn0);
            unsigned long long b1 = __ballot(cn1 && pn1);
            unsigned long long b2 = __ballot(cn2 && pn2);
            unsigned long long b3 = __ballot(cn3 && pn3);
            int cA = __popcll(b0 & 0xFFFFFFFFull) + __popcll(b1 & 0xFFFFFFFFull)
                   + __popcll(b2 & 0xFFFFFFFFull) + __popcll(b3 & 0xFFFFFFFFull);
            int cB = __popcll(b0 >> 32) + __popcll(b1 >> 32)
                   + __popcll(b2 >> 32) + __popcll(b3 >> 32);
            fire |= (cA >= ACT_THR) | (cB >= ACT_THR);
            if (fire) break;                    // any-semantics: exact early exit
        }
        if (ln == 0) outpred[cell] = fire ? 1.0f : 0.0f;
    }
}

// ---------------------------------------------------------------------------
extern "C" void kernel_launch(void* const* d_in, const int* in_sizes, int n_in,
                              void* d_out, int out_size, void* d_ws, size_t ws_size,
                              hipStream_t stream) {
    const int*   x    = (const int*)d_in[0];
    const float* mod  = (const float*)d_in[1];
    const void*  prev = d_in[2];                 // bool array (dtype auto-detected)
    const int*   conn = (const int*)d_in[3];
    const float* vol  = (const float*)d_in[4];
    const float* cons = (const float*)d_in[5];
    float* out = (float*)d_out;  // [0..N) new_active, [N..2N) new_predictive, [2N] acc

    char* ws = (char*)d_ws;
    uint32_t* prevbits  = (uint32_t*)(ws + 0);         // 2048 B
    uint32_t* newbits   = (uint32_t*)(ws + 2048);      // 2048 B
    int*      learnflag = (int*)(ws + 4096);
    int*      acount    = (int*)(ws + 4160);
    int*      acols     = (int*)(ws + 4352);           // 4 KiB
    unsigned char* pred1   = (unsigned char*)(ws + 16384);  // 16 KiB
    unsigned char* bestseg = (unsigned char*)(ws + 32768);  // 16 KiB

    plan_kernel<<<1, 1024, 0, stream>>>(prev, x, mod, prevbits, acols, acount,
                                        learnflag);
    phase1_kernel<<<NB, 256, 0, stream>>>(prevbits, acols, acount, conn, vol,
                                          cons, pred1, bestseg);
    mid_kernel<<<1, 1024, 0, stream>>>(x, pred1, newbits, out);
    phase3_kernel<<<NB, 256, 0, stream>>>(prevbits, newbits, acols, acount,
                                          learnflag, mod, conn, vol, cons,
                                          bestseg, out + NUM_CELLS);
}